// Round 6
// baseline (301.696 us; speedup 1.0000x reference)
//
#include <hip/hip_runtime.h>
#include <hip/hip_fp16.h>
#include <math.h>

#define N_NODES 100000
#define N_EDGES 1250000
#define D 64
#define EPS 1e-8f

#define ZERO_BLOCKS 391     // ceil(100000/256)
#define GEMM_BLOCKS 1024
#define RANK_BLOCKS 4883    // ceil(1250000/256)
#define EDGE_BLOCKS 4883    // ceil(1250000/256)
#define NODE_BLOCKS 391     // ceil(100000/256)

// ---------------------------------------------------------------------------
// Fused: cnt+deg zeroing (blocks 0..390) + hn = normalize(tanh(xW^T+b)) -> fp16
// ---------------------------------------------------------------------------
__global__ __launch_bounds__(256) void k_gemm_zero(
    const float* __restrict__ x, const float* __restrict__ W,
    const float* __restrict__ b, __half* __restrict__ hn,
    int* __restrict__ cnt, float* __restrict__ deg)
{
    if (blockIdx.x < ZERO_BLOCKS) {
        int i = blockIdx.x * 256 + threadIdx.x;
        if (i < N_NODES) { cnt[i] = 0; deg[i] = 0.0f; }
        return;
    }
    __shared__ float xrow[4][72];
    const int lane = threadIdx.x & 63;
    const int wid  = threadIdx.x >> 6;

    float Wreg[64];
    const float4* Wv = (const float4*)(W + lane * D);
    #pragma unroll
    for (int q = 0; q < 16; ++q) {
        float4 w4 = Wv[q];
        Wreg[4*q+0] = w4.x; Wreg[4*q+1] = w4.y;
        Wreg[4*q+2] = w4.z; Wreg[4*q+3] = w4.w;
    }
    const float bj = b[lane];
    float* xl = xrow[wid];

    const int wave   = (blockIdx.x - ZERO_BLOCKS) * 4 + wid;
    const int nwaves = GEMM_BLOCKS * 4;

    for (int row = wave; row < N_NODES; row += nwaves) {
        float xv = x[(size_t)row * D + lane];
        xl[lane] = xv;
        float acc = bj;
        #pragma unroll
        for (int q = 0; q < 16; ++q) {
            float4 xk4 = *(const float4*)(xl + 4*q);
            acc = fmaf(xk4.x, Wreg[4*q+0], acc);
            acc = fmaf(xk4.y, Wreg[4*q+1], acc);
            acc = fmaf(xk4.z, Wreg[4*q+2], acc);
            acc = fmaf(xk4.w, Wreg[4*q+3], acc);
        }
        float h = tanhf(acc);
        float s = h * h;
        #pragma unroll
        for (int m = 32; m >= 1; m >>= 1) s += __shfl_xor(s, m, 64);
        float nrm = fmaxf(sqrtf(s), EPS);
        hn[(size_t)row * D + lane] = __float2half_rn(h / nrm);
    }
}

// ---------------------------------------------------------------------------
// Fused: atomic rank pass (1/3 of blocks) CONCURRENT with edge-order cosine
// (2/3 of blocks). Cosine also accumulates deg[dst] via FIRE-AND-FORGET float
// atomics (no return -> no latency chain; hides under the gather latency).
// ---------------------------------------------------------------------------
__device__ __forceinline__ float dot8h(float4 a, float4 c)
{
    const __half2* ah = (const __half2*)&a;
    const __half2* ch = (const __half2*)&c;
    float p = 0.0f;
    #pragma unroll
    for (int q = 0; q < 4; ++q) {
        float2 af = __half22float2(ah[q]);
        float2 cf = __half22float2(ch[q]);
        p = fmaf(af.x, cf.x, p);
        p = fmaf(af.y, cf.y, p);
    }
    return p;
}

__global__ __launch_bounds__(256) void k_rank_cos(
    const int* __restrict__ ei, int* __restrict__ cnt, int* __restrict__ rank,
    const __half* __restrict__ hn, float* __restrict__ wout,
    float* __restrict__ deg)
{
    const int b = blockIdx.x;
    const int r = b % 3;
    if (r == 0) {
        // ---- rank role ----
        int e = (b / 3) * 256 + threadIdx.x;
        if (e < N_EDGES) {
            int d = ei[N_EDGES + e];
            rank[e] = atomicAdd(cnt + d, 1);
        }
        return;
    }
    // ---- cosine role: 8 lanes/edge, 4 edges/group, 8 gathers in flight ----
    int cb = (b / 3) * 2 + (r - 1);            // 0 .. 9765
    int t = cb * 256 + threadIdx.x;
    int g = t >> 3, sub = t & 7;
    if (g >= N_EDGES / 4) return;
    int e0 = g * 4;
    int4 ss = *(const int4*)(ei + e0);
    int4 dd = *(const int4*)(ei + N_EDGES + e0);

    float4 a0 = ((const float4*)(hn + (size_t)ss.x * D))[sub];
    float4 c0 = ((const float4*)(hn + (size_t)dd.x * D))[sub];
    float4 a1 = ((const float4*)(hn + (size_t)ss.y * D))[sub];
    float4 c1 = ((const float4*)(hn + (size_t)dd.y * D))[sub];
    float4 a2 = ((const float4*)(hn + (size_t)ss.z * D))[sub];
    float4 c2 = ((const float4*)(hn + (size_t)dd.z * D))[sub];
    float4 a3 = ((const float4*)(hn + (size_t)ss.w * D))[sub];
    float4 c3 = ((const float4*)(hn + (size_t)dd.w * D))[sub];

    float p0 = dot8h(a0, c0);
    float p1 = dot8h(a1, c1);
    float p2 = dot8h(a2, c2);
    float p3 = dot8h(a3, c3);
    p0 += __shfl_xor(p0, 1, 64);  p1 += __shfl_xor(p1, 1, 64);
    p2 += __shfl_xor(p2, 1, 64);  p3 += __shfl_xor(p3, 1, 64);
    p0 += __shfl_xor(p0, 2, 64);  p1 += __shfl_xor(p1, 2, 64);
    p2 += __shfl_xor(p2, 2, 64);  p3 += __shfl_xor(p3, 2, 64);
    p0 += __shfl_xor(p0, 4, 64);  p1 += __shfl_xor(p1, 4, 64);
    p2 += __shfl_xor(p2, 4, 64);  p3 += __shfl_xor(p3, 4, 64);

    if (sub == 0) {
        float w0 = fmaxf(p0, 0.0f);
        float w1 = fmaxf(p1, 0.0f);
        float w2 = fmaxf(p2, 0.0f);
        float w3 = fmaxf(p3, 0.0f);
        *(float4*)(wout + e0) = make_float4(w0, w1, w2, w3);
        atomicAdd(deg + dd.x, w0);
        atomicAdd(deg + dd.y, w1);
        atomicAdd(deg + dd.z, w2);
        atomicAdd(deg + dd.w, w3);
    }
}

// ---------------------------------------------------------------------------
// Scan: exclusive prefix sum of cnt[100000] -> rowptr (partial; consumers add
// boff[i>>8] on the fly -- scan3 eliminated)
// ---------------------------------------------------------------------------
__device__ __forceinline__ int wave_iscan(int v, int lane)
{
    int incl = v;
    #pragma unroll
    for (int m = 1; m < 64; m <<= 1) {
        int o = __shfl_up(incl, m, 64);
        if (lane >= m) incl += o;
    }
    return incl;
}

__global__ __launch_bounds__(256) void k_scan1(
    const int* __restrict__ cnt, int* __restrict__ rowptr, int* __restrict__ bsum)
{
    __shared__ int wsum[4];
    int t = threadIdx.x, b = blockIdx.x;
    int i = b * 256 + t;
    int lane = t & 63, wid = t >> 6;
    int v = (i < N_NODES) ? cnt[i] : 0;
    int incl = wave_iscan(v, lane);
    if (lane == 63) wsum[wid] = incl;
    __syncthreads();
    int off = 0;
    #pragma unroll
    for (int k = 0; k < 4; ++k) if (k < wid) off += wsum[k];
    if (i < N_NODES) rowptr[i] = off + incl - v;
    if (t == 255) bsum[b] = off + incl;
}

__global__ __launch_bounds__(512) void k_scan2(
    const int* __restrict__ bsum, int* __restrict__ boff, int nblk,
    int* __restrict__ rowptr)
{
    __shared__ int wsum[8];
    int t = threadIdx.x;
    int lane = t & 63, wid = t >> 6;
    int v = (t < nblk) ? bsum[t] : 0;
    int incl = wave_iscan(v, lane);
    if (lane == 63) wsum[wid] = incl;
    __syncthreads();
    int off = 0;
    #pragma unroll
    for (int k = 0; k < 8; ++k) if (k < wid) off += wsum[k];
    if (t < nblk) boff[t] = off + incl - v;
    if (t == 0) rowptr[N_NODES] = N_EDGES;   // final value, no boff add
}

// ---------------------------------------------------------------------------
// Fused: CSR placement (edge blocks) + elementwise dis/y0 (node blocks).
// dis/y0 reads deg (computed by k_rank_cos atomics) -- no pairs re-read.
// ---------------------------------------------------------------------------
__global__ __launch_bounds__(256) void k_place_dis(
    const int* __restrict__ ei, const int* __restrict__ rank_pos,
    const int* __restrict__ rowptr, const int* __restrict__ boff,
    const float* __restrict__ wsrc, int2* __restrict__ pairs,
    const float* __restrict__ deg, const float* __restrict__ mask,
    float* __restrict__ dis, float* __restrict__ y)
{
    if (blockIdx.x >= EDGE_BLOCKS) {
        int node = (blockIdx.x - EDGE_BLOCKS) * 256 + threadIdx.x;
        if (node < N_NODES) {
            float di = rsqrtf(fmaxf(deg[node] + 1.0f, EPS));   // +1 self-loop
            dis[node] = di;
            y[node] = di * fmaxf(mask[node], 0.0f);
        }
        return;
    }
    int e = blockIdx.x * 256 + threadIdx.x;
    if (e >= N_EDGES) return;
    int s = ei[e];
    int d = ei[N_EDGES + e];
    int pos = rowptr[d] + boff[d >> 8] + rank_pos[e];
    pairs[pos] = make_int2(s, __float_as_int(wsrc[e]));
}

// ---------------------------------------------------------------------------
// APPNP step in y-domain, 8 lanes per node (avg degree 12.5), no atomics:
// f'_i = (1-a) * dis_i * ( sum_j w_ij*y_j + y_i ) + a*relu(mask_i)
// y'_i = dis_i * f'_i
// ---------------------------------------------------------------------------
__global__ __launch_bounds__(256) void k_spmv(
    const int* __restrict__ rowptr, const int* __restrict__ boff,
    const int2* __restrict__ pairs,
    const float* __restrict__ y_in, const float* __restrict__ dis,
    const float* __restrict__ mask, const float* __restrict__ alpha_p,
    float* __restrict__ y_out, float* __restrict__ f_out)
{
    int t = blockIdx.x * 256 + threadIdx.x;
    int node = t >> 3, l = t & 7;
    if (node >= N_NODES) return;
    int beg = rowptr[node] + boff[node >> 8];
    int np1 = node + 1;
    int end = rowptr[np1] + (np1 < N_NODES ? boff[np1 >> 8] : 0);
    float sum = 0.0f;
    for (int j = beg + l; j < end; j += 8) {
        int2 p = pairs[j];
        sum += __int_as_float(p.y) * y_in[p.x];
    }
    sum += __shfl_xor(sum, 1, 64);
    sum += __shfl_xor(sum, 2, 64);
    sum += __shfl_xor(sum, 4, 64);
    if (l == 0) {
        float di = dis[node];
        float alpha = alpha_p[0];
        float f0 = fmaxf(mask[node], 0.0f);
        float fn = (1.0f - alpha) * di * (sum + y_in[node]) + alpha * f0;
        f_out[node] = fn;
        y_out[node] = di * fn;
    }
}

extern "C" void kernel_launch(void* const* d_in, const int* in_sizes, int n_in,
                              void* d_out, int out_size, void* d_ws, size_t ws_size,
                              hipStream_t stream)
{
    const float* x     = (const float*)d_in[0];
    const float* mask  = (const float*)d_in[1];
    const int*   ei    = (const int*)  d_in[2];
    const float* W     = (const float*)d_in[3];
    const float* b     = (const float*)d_in[4];
    const float* alpha = (const float*)d_in[5];

    float* out_f = (float*)d_out;
    float* out_w = (float*)d_out + N_NODES;

    // workspace layout (float-element offsets)
    float* ws = (float*)d_ws;
    __half* hn     = (__half*)ws;                  // 6.4M halves (3.2M floats)
    int2*  pairs   = (int2*) (ws + 3200000);       // 1.25M x 8B
    int*   rank    = (int*)  (ws + 5700000);       // 1.25M
    int*   cnt     = (int*)  (ws + 6950000);       // 100k
    int*   rowptr  = (int*)  (ws + 7050000);       // 100001 (alloc 100016)
    float* dis     =          ws + 7150016;        // 100k
    float* y_a     =          ws + 7250016;        // 100k
    float* y_b     =          ws + 7350016;        // 100k
    float* f_scr   =          ws + 7450016;        // 100k (deg before spmv, f dump after)
    int*   bsum    = (int*)  (ws + 7550016);       // 391 (alloc 512)
    int*   boff    = (int*)  (ws + 7550528);       // 391

    float* deg = f_scr;   // deg's last read (k_place_dis) precedes f_scr's first write

    const int spmvBlocks = (int)(((long long)N_NODES * 8 + 255) / 256);   // 3125

    // K0: zero(cnt,deg) + gemm_norm fused
    k_gemm_zero<<<ZERO_BLOCKS + GEMM_BLOCKS, 256, 0, stream>>>(x, W, b, hn, cnt, deg);
    // K1: atomic rank  CONCURRENT WITH  edge-order cosine (writes out_w + deg)
    k_rank_cos<<<3 * RANK_BLOCKS, 256, 0, stream>>>(ei, cnt, rank, hn, out_w, deg);
    // K2..K3: rowptr scan (partial rowptr + boff; consumers fold boff on the fly)
    k_scan1<<<NODE_BLOCKS, 256, 0, stream>>>(cnt, rowptr, bsum);
    k_scan2<<<1, 512, 0, stream>>>(bsum, boff, NODE_BLOCKS, rowptr);
    // K4: CSR placement (src, w) + elementwise dis/y0
    k_place_dis<<<EDGE_BLOCKS + NODE_BLOCKS, 256, 0, stream>>>(
        ei, rank, rowptr, boff, out_w, pairs, deg, mask, dis, y_a);

    // K5..K9: 5 APPNP steps in y-domain; last writes f to d_out
    k_spmv<<<spmvBlocks, 256, 0, stream>>>(rowptr, boff, pairs, y_a, dis, mask, alpha, y_b, f_scr);
    k_spmv<<<spmvBlocks, 256, 0, stream>>>(rowptr, boff, pairs, y_b, dis, mask, alpha, y_a, f_scr);
    k_spmv<<<spmvBlocks, 256, 0, stream>>>(rowptr, boff, pairs, y_a, dis, mask, alpha, y_b, f_scr);
    k_spmv<<<spmvBlocks, 256, 0, stream>>>(rowptr, boff, pairs, y_b, dis, mask, alpha, y_a, f_scr);
    k_spmv<<<spmvBlocks, 256, 0, stream>>>(rowptr, boff, pairs, y_a, dis, mask, alpha, y_b, out_f);
}

// Round 7
// 248.021 us; speedup vs baseline: 1.2164x; 1.2164x over previous
//
#include <hip/hip_runtime.h>
#include <hip/hip_fp16.h>
#include <math.h>

#define N_NODES 100000
#define N_EDGES 1250000
#define D 64
#define EPS 1e-8f

#define ZERO_BLOCKS 391     // ceil(100000/256)
#define GEMM_BLOCKS 1024
#define RANK_BLOCKS 4883    // ceil(1250000/256)
#define NODE_BLOCKS 391     // ceil(100000/256)

// ---------------------------------------------------------------------------
// Fused: cnt zeroing (blocks 0..390) + hn = normalize(tanh(xW^T+b)) -> fp16
// ---------------------------------------------------------------------------
__global__ __launch_bounds__(256) void k_gemm_zero(
    const float* __restrict__ x, const float* __restrict__ W,
    const float* __restrict__ b, __half* __restrict__ hn, int* __restrict__ cnt)
{
    if (blockIdx.x < ZERO_BLOCKS) {
        int i = blockIdx.x * 256 + threadIdx.x;
        if (i < N_NODES) cnt[i] = 0;
        return;
    }
    __shared__ float xrow[4][72];
    const int lane = threadIdx.x & 63;
    const int wid  = threadIdx.x >> 6;

    float Wreg[64];
    const float4* Wv = (const float4*)(W + lane * D);
    #pragma unroll
    for (int q = 0; q < 16; ++q) {
        float4 w4 = Wv[q];
        Wreg[4*q+0] = w4.x; Wreg[4*q+1] = w4.y;
        Wreg[4*q+2] = w4.z; Wreg[4*q+3] = w4.w;
    }
    const float bj = b[lane];
    float* xl = xrow[wid];

    const int wave   = (blockIdx.x - ZERO_BLOCKS) * 4 + wid;
    const int nwaves = GEMM_BLOCKS * 4;

    for (int row = wave; row < N_NODES; row += nwaves) {
        float xv = x[(size_t)row * D + lane];
        xl[lane] = xv;
        float acc = bj;
        #pragma unroll
        for (int q = 0; q < 16; ++q) {
            float4 xk4 = *(const float4*)(xl + 4*q);
            acc = fmaf(xk4.x, Wreg[4*q+0], acc);
            acc = fmaf(xk4.y, Wreg[4*q+1], acc);
            acc = fmaf(xk4.z, Wreg[4*q+2], acc);
            acc = fmaf(xk4.w, Wreg[4*q+3], acc);
        }
        float h = tanhf(acc);
        float s = h * h;
        #pragma unroll
        for (int m = 32; m >= 1; m >>= 1) s += __shfl_xor(s, m, 64);
        float nrm = fmaxf(sqrtf(s), EPS);
        hn[(size_t)row * D + lane] = __float2half_rn(h / nrm);
    }
}

// ---------------------------------------------------------------------------
// Fused: atomic rank pass (1/3 of blocks) CONCURRENT with edge-order cosine
// (2/3 of blocks). NO deg atomics (round-6 lesson: 1.25M random float
// atomics doubled the kernel). Cosine writes out_w[e] only.
// ---------------------------------------------------------------------------
__device__ __forceinline__ float dot8h(float4 a, float4 c)
{
    const __half2* ah = (const __half2*)&a;
    const __half2* ch = (const __half2*)&c;
    float p = 0.0f;
    #pragma unroll
    for (int q = 0; q < 4; ++q) {
        float2 af = __half22float2(ah[q]);
        float2 cf = __half22float2(ch[q]);
        p = fmaf(af.x, cf.x, p);
        p = fmaf(af.y, cf.y, p);
    }
    return p;
}

__global__ __launch_bounds__(256) void k_rank_cos(
    const int* __restrict__ ei, int* __restrict__ cnt, int* __restrict__ rank,
    const __half* __restrict__ hn, float* __restrict__ wout)
{
    const int b = blockIdx.x;
    const int r = b % 3;
    if (r == 0) {
        // ---- rank role ----
        int e = (b / 3) * 256 + threadIdx.x;
        if (e < N_EDGES) {
            int d = ei[N_EDGES + e];
            rank[e] = atomicAdd(cnt + d, 1);
        }
        return;
    }
    // ---- cosine role: 8 lanes/edge, 4 edges/group, 8 gathers in flight ----
    int cb = (b / 3) * 2 + (r - 1);            // 0 .. 9765
    int t = cb * 256 + threadIdx.x;
    int g = t >> 3, sub = t & 7;
    if (g >= N_EDGES / 4) return;
    int e0 = g * 4;
    int4 ss = *(const int4*)(ei + e0);
    int4 dd = *(const int4*)(ei + N_EDGES + e0);

    float4 a0 = ((const float4*)(hn + (size_t)ss.x * D))[sub];
    float4 c0 = ((const float4*)(hn + (size_t)dd.x * D))[sub];
    float4 a1 = ((const float4*)(hn + (size_t)ss.y * D))[sub];
    float4 c1 = ((const float4*)(hn + (size_t)dd.y * D))[sub];
    float4 a2 = ((const float4*)(hn + (size_t)ss.z * D))[sub];
    float4 c2 = ((const float4*)(hn + (size_t)dd.z * D))[sub];
    float4 a3 = ((const float4*)(hn + (size_t)ss.w * D))[sub];
    float4 c3 = ((const float4*)(hn + (size_t)dd.w * D))[sub];

    float p0 = dot8h(a0, c0);
    float p1 = dot8h(a1, c1);
    float p2 = dot8h(a2, c2);
    float p3 = dot8h(a3, c3);
    p0 += __shfl_xor(p0, 1, 64);  p1 += __shfl_xor(p1, 1, 64);
    p2 += __shfl_xor(p2, 1, 64);  p3 += __shfl_xor(p3, 1, 64);
    p0 += __shfl_xor(p0, 2, 64);  p1 += __shfl_xor(p1, 2, 64);
    p2 += __shfl_xor(p2, 2, 64);  p3 += __shfl_xor(p3, 2, 64);
    p0 += __shfl_xor(p0, 4, 64);  p1 += __shfl_xor(p1, 4, 64);
    p2 += __shfl_xor(p2, 4, 64);  p3 += __shfl_xor(p3, 4, 64);

    if (sub == 0) {
        *(float4*)(wout + e0) = make_float4(
            fmaxf(p0, 0.0f), fmaxf(p1, 0.0f), fmaxf(p2, 0.0f), fmaxf(p3, 0.0f));
    }
}

// ---------------------------------------------------------------------------
// Scan: exclusive prefix sum of cnt[100000] -> rowptr (partial; consumers add
// boff[i>>8] on the fly)
// ---------------------------------------------------------------------------
__device__ __forceinline__ int wave_iscan(int v, int lane)
{
    int incl = v;
    #pragma unroll
    for (int m = 1; m < 64; m <<= 1) {
        int o = __shfl_up(incl, m, 64);
        if (lane >= m) incl += o;
    }
    return incl;
}

__global__ __launch_bounds__(256) void k_scan1(
    const int* __restrict__ cnt, int* __restrict__ rowptr, int* __restrict__ bsum)
{
    __shared__ int wsum[4];
    int t = threadIdx.x, b = blockIdx.x;
    int i = b * 256 + t;
    int lane = t & 63, wid = t >> 6;
    int v = (i < N_NODES) ? cnt[i] : 0;
    int incl = wave_iscan(v, lane);
    if (lane == 63) wsum[wid] = incl;
    __syncthreads();
    int off = 0;
    #pragma unroll
    for (int k = 0; k < 4; ++k) if (k < wid) off += wsum[k];
    if (i < N_NODES) rowptr[i] = off + incl - v;
    if (t == 255) bsum[b] = off + incl;
}

__global__ __launch_bounds__(512) void k_scan2(
    const int* __restrict__ bsum, int* __restrict__ boff, int nblk,
    int* __restrict__ rowptr)
{
    __shared__ int wsum[8];
    int t = threadIdx.x;
    int lane = t & 63, wid = t >> 6;
    int v = (t < nblk) ? bsum[t] : 0;
    int incl = wave_iscan(v, lane);
    if (lane == 63) wsum[wid] = incl;
    __syncthreads();
    int off = 0;
    #pragma unroll
    for (int k = 0; k < 8; ++k) if (k < wid) off += wsum[k];
    if (t < nblk) boff[t] = off + incl - v;
    if (t == 0) rowptr[N_NODES] = N_EDGES;   // final value, no boff add
}

// ---------------------------------------------------------------------------
// CSR placement: pairs[pos] = (src, w); boff folded on the fly
// ---------------------------------------------------------------------------
__global__ __launch_bounds__(256) void k_place(
    const int* __restrict__ ei, const int* __restrict__ rank_pos,
    const int* __restrict__ rowptr, const int* __restrict__ boff,
    const float* __restrict__ wsrc, int2* __restrict__ pairs)
{
    int e = blockIdx.x * 256 + threadIdx.x;
    if (e >= N_EDGES) return;
    int s = ei[e];
    int d = ei[N_EDGES + e];
    int pos = rowptr[d] + boff[d >> 8] + rank_pos[e];
    pairs[pos] = make_int2(s, __float_as_int(wsrc[e]));
}

// ---------------------------------------------------------------------------
// deg via segment-sum (sequential pairs read, NO atomics), 8 lanes per node;
// dis = rsqrt(deg+1); y0 = dis*relu(mask)
// ---------------------------------------------------------------------------
__global__ __launch_bounds__(256) void k_dis_y(
    const int* __restrict__ rowptr, const int* __restrict__ boff,
    const int2* __restrict__ pairs, const float* __restrict__ mask,
    float* __restrict__ dis, float* __restrict__ y)
{
    int t = blockIdx.x * 256 + threadIdx.x;
    int node = t >> 3, l = t & 7;
    if (node >= N_NODES) return;
    int beg = rowptr[node] + boff[node >> 8];
    int np1 = node + 1;
    int end = rowptr[np1] + (np1 < N_NODES ? boff[np1 >> 8] : 0);
    float s = 0.0f;
    for (int j = beg + l; j < end; j += 8)
        s += __int_as_float(pairs[j].y);
    s += __shfl_xor(s, 1, 64);
    s += __shfl_xor(s, 2, 64);
    s += __shfl_xor(s, 4, 64);
    if (l == 0) {
        float di = rsqrtf(fmaxf(s + 1.0f, EPS));   // +1 self-loop
        dis[node] = di;
        y[node] = di * fmaxf(mask[node], 0.0f);
    }
}

// ---------------------------------------------------------------------------
// APPNP step in y-domain, 8 lanes per node (avg degree 12.5), no atomics:
// f'_i = (1-a) * dis_i * ( sum_j w_ij*y_j + y_i ) + a*relu(mask_i)
// y'_i = dis_i * f'_i
// ---------------------------------------------------------------------------
__global__ __launch_bounds__(256) void k_spmv(
    const int* __restrict__ rowptr, const int* __restrict__ boff,
    const int2* __restrict__ pairs,
    const float* __restrict__ y_in, const float* __restrict__ dis,
    const float* __restrict__ mask, const float* __restrict__ alpha_p,
    float* __restrict__ y_out, float* __restrict__ f_out)
{
    int t = blockIdx.x * 256 + threadIdx.x;
    int node = t >> 3, l = t & 7;
    if (node >= N_NODES) return;
    int beg = rowptr[node] + boff[node >> 8];
    int np1 = node + 1;
    int end = rowptr[np1] + (np1 < N_NODES ? boff[np1 >> 8] : 0);
    float sum = 0.0f;
    for (int j = beg + l; j < end; j += 8) {
        int2 p = pairs[j];
        sum += __int_as_float(p.y) * y_in[p.x];
    }
    sum += __shfl_xor(sum, 1, 64);
    sum += __shfl_xor(sum, 2, 64);
    sum += __shfl_xor(sum, 4, 64);
    if (l == 0) {
        float di = dis[node];
        float alpha = alpha_p[0];
        float f0 = fmaxf(mask[node], 0.0f);
        float fn = (1.0f - alpha) * di * (sum + y_in[node]) + alpha * f0;
        f_out[node] = fn;
        y_out[node] = di * fn;
    }
}

extern "C" void kernel_launch(void* const* d_in, const int* in_sizes, int n_in,
                              void* d_out, int out_size, void* d_ws, size_t ws_size,
                              hipStream_t stream)
{
    const float* x     = (const float*)d_in[0];
    const float* mask  = (const float*)d_in[1];
    const int*   ei    = (const int*)  d_in[2];
    const float* W     = (const float*)d_in[3];
    const float* b     = (const float*)d_in[4];
    const float* alpha = (const float*)d_in[5];

    float* out_f = (float*)d_out;
    float* out_w = (float*)d_out + N_NODES;

    // workspace layout (float-element offsets)
    float* ws = (float*)d_ws;
    __half* hn     = (__half*)ws;                  // 6.4M halves (3.2M floats)
    int2*  pairs   = (int2*) (ws + 3200000);       // 1.25M x 8B
    int*   rank    = (int*)  (ws + 5700000);       // 1.25M
    int*   cnt     = (int*)  (ws + 6950000);       // 100k
    int*   rowptr  = (int*)  (ws + 7050000);       // 100001 (alloc 100016)
    float* dis     =          ws + 7150016;        // 100k
    float* y_a     =          ws + 7250016;        // 100k
    float* y_b     =          ws + 7350016;        // 100k
    float* f_scr   =          ws + 7450016;        // 100k
    int*   bsum    = (int*)  (ws + 7550016);       // 391 (alloc 512)
    int*   boff    = (int*)  (ws + 7550528);       // 391

    const int edgeBlocks = (N_EDGES + 255) / 256;                         // 4883
    const int segBlocks  = (int)(((long long)N_NODES * 8 + 255) / 256);   // 3125

    // K0: zero(cnt) + gemm_norm fused
    k_gemm_zero<<<ZERO_BLOCKS + GEMM_BLOCKS, 256, 0, stream>>>(x, W, b, hn, cnt);
    // K1: atomic rank  CONCURRENT WITH  edge-order cosine (writes out_w)
    k_rank_cos<<<3 * RANK_BLOCKS, 256, 0, stream>>>(ei, cnt, rank, hn, out_w);
    // K2..K3: rowptr scan (partial rowptr + boff; consumers fold boff on the fly)
    k_scan1<<<NODE_BLOCKS, 256, 0, stream>>>(cnt, rowptr, bsum);
    k_scan2<<<1, 512, 0, stream>>>(bsum, boff, NODE_BLOCKS, rowptr);
    // K4: CSR placement (src, w)
    k_place<<<edgeBlocks, 256, 0, stream>>>(ei, rank, rowptr, boff, out_w, pairs);
    // K5: deg -> dis, y0 (segment-sum, no atomics)
    k_dis_y<<<segBlocks, 256, 0, stream>>>(rowptr, boff, pairs, mask, dis, y_a);

    // K6..K10: 5 APPNP steps in y-domain; last writes f to d_out
    k_spmv<<<segBlocks, 256, 0, stream>>>(rowptr, boff, pairs, y_a, dis, mask, alpha, y_b, f_scr);
    k_spmv<<<segBlocks, 256, 0, stream>>>(rowptr, boff, pairs, y_b, dis, mask, alpha, y_a, f_scr);
    k_spmv<<<segBlocks, 256, 0, stream>>>(rowptr, boff, pairs, y_a, dis, mask, alpha, y_b, f_scr);
    k_spmv<<<segBlocks, 256, 0, stream>>>(rowptr, boff, pairs, y_b, dis, mask, alpha, y_a, f_scr);
    k_spmv<<<segBlocks, 256, 0, stream>>>(rowptr, boff, pairs, y_a, dis, mask, alpha, y_b, out_f);
}

// Round 8
// 239.352 us; speedup vs baseline: 1.2605x; 1.0362x over previous
//
#include <hip/hip_runtime.h>
#include <hip/hip_fp16.h>
#include <math.h>

#define N_NODES 100000
#define N_EDGES 1250000
#define D 64
#define EPS 1e-8f

#define ZERO_BLOCKS 391     // ceil(100000/256)
#define GEMM_BLOCKS 1024
#define RANK_BLOCKS 4883    // ceil(1250000/256)
#define NODE_BLOCKS 391     // ceil(100000/256)

// ---------------------------------------------------------------------------
// Fused: cnt zeroing (blocks 0..390) + hn = normalize(tanh(xW^T+b)) -> fp16
// ---------------------------------------------------------------------------
__global__ __launch_bounds__(256) void k_gemm_zero(
    const float* __restrict__ x, const float* __restrict__ W,
    const float* __restrict__ b, __half* __restrict__ hn, int* __restrict__ cnt)
{
    if (blockIdx.x < ZERO_BLOCKS) {
        int i = blockIdx.x * 256 + threadIdx.x;
        if (i < N_NODES) cnt[i] = 0;
        return;
    }
    __shared__ float xrow[4][72];
    const int lane = threadIdx.x & 63;
    const int wid  = threadIdx.x >> 6;

    float Wreg[64];
    const float4* Wv = (const float4*)(W + lane * D);
    #pragma unroll
    for (int q = 0; q < 16; ++q) {
        float4 w4 = Wv[q];
        Wreg[4*q+0] = w4.x; Wreg[4*q+1] = w4.y;
        Wreg[4*q+2] = w4.z; Wreg[4*q+3] = w4.w;
    }
    const float bj = b[lane];
    float* xl = xrow[wid];

    const int wave   = (blockIdx.x - ZERO_BLOCKS) * 4 + wid;
    const int nwaves = GEMM_BLOCKS * 4;

    for (int row = wave; row < N_NODES; row += nwaves) {
        float xv = x[(size_t)row * D + lane];
        xl[lane] = xv;
        float acc = bj;
        #pragma unroll
        for (int q = 0; q < 16; ++q) {
            float4 xk4 = *(const float4*)(xl + 4*q);
            acc = fmaf(xk4.x, Wreg[4*q+0], acc);
            acc = fmaf(xk4.y, Wreg[4*q+1], acc);
            acc = fmaf(xk4.z, Wreg[4*q+2], acc);
            acc = fmaf(xk4.w, Wreg[4*q+3], acc);
        }
        float h = tanhf(acc);
        float s = h * h;
        #pragma unroll
        for (int m = 32; m >= 1; m >>= 1) s += __shfl_xor(s, m, 64);
        float nrm = fmaxf(sqrtf(s), EPS);
        hn[(size_t)row * D + lane] = __float2half_rn(h / nrm);
    }
}

// ---------------------------------------------------------------------------
// Fused: atomic rank pass (1/3 of blocks) CONCURRENT with edge-order cosine
// (2/3 of blocks). NO deg atomics (round-6 lesson: 1.25M random float
// atomics doubled the kernel). Cosine writes out_w[e] only.
// ---------------------------------------------------------------------------
__device__ __forceinline__ float dot8h(float4 a, float4 c)
{
    const __half2* ah = (const __half2*)&a;
    const __half2* ch = (const __half2*)&c;
    float p = 0.0f;
    #pragma unroll
    for (int q = 0; q < 4; ++q) {
        float2 af = __half22float2(ah[q]);
        float2 cf = __half22float2(ch[q]);
        p = fmaf(af.x, cf.x, p);
        p = fmaf(af.y, cf.y, p);
    }
    return p;
}

__global__ __launch_bounds__(256) void k_rank_cos(
    const int* __restrict__ ei, int* __restrict__ cnt, int* __restrict__ rank,
    const __half* __restrict__ hn, float* __restrict__ wout)
{
    const int b = blockIdx.x;
    const int r = b % 3;
    if (r == 0) {
        // ---- rank role ----
        int e = (b / 3) * 256 + threadIdx.x;
        if (e < N_EDGES) {
            int d = ei[N_EDGES + e];
            rank[e] = atomicAdd(cnt + d, 1);
        }
        return;
    }
    // ---- cosine role: 8 lanes/edge, 4 edges/group, 8 gathers in flight ----
    int cb = (b / 3) * 2 + (r - 1);            // 0 .. 9765
    int t = cb * 256 + threadIdx.x;
    int g = t >> 3, sub = t & 7;
    if (g >= N_EDGES / 4) return;
    int e0 = g * 4;
    int4 ss = *(const int4*)(ei + e0);
    int4 dd = *(const int4*)(ei + N_EDGES + e0);

    float4 a0 = ((const float4*)(hn + (size_t)ss.x * D))[sub];
    float4 c0 = ((const float4*)(hn + (size_t)dd.x * D))[sub];
    float4 a1 = ((const float4*)(hn + (size_t)ss.y * D))[sub];
    float4 c1 = ((const float4*)(hn + (size_t)dd.y * D))[sub];
    float4 a2 = ((const float4*)(hn + (size_t)ss.z * D))[sub];
    float4 c2 = ((const float4*)(hn + (size_t)dd.z * D))[sub];
    float4 a3 = ((const float4*)(hn + (size_t)ss.w * D))[sub];
    float4 c3 = ((const float4*)(hn + (size_t)dd.w * D))[sub];

    float p0 = dot8h(a0, c0);
    float p1 = dot8h(a1, c1);
    float p2 = dot8h(a2, c2);
    float p3 = dot8h(a3, c3);
    p0 += __shfl_xor(p0, 1, 64);  p1 += __shfl_xor(p1, 1, 64);
    p2 += __shfl_xor(p2, 1, 64);  p3 += __shfl_xor(p3, 1, 64);
    p0 += __shfl_xor(p0, 2, 64);  p1 += __shfl_xor(p1, 2, 64);
    p2 += __shfl_xor(p2, 2, 64);  p3 += __shfl_xor(p3, 2, 64);
    p0 += __shfl_xor(p0, 4, 64);  p1 += __shfl_xor(p1, 4, 64);
    p2 += __shfl_xor(p2, 4, 64);  p3 += __shfl_xor(p3, 4, 64);

    if (sub == 0) {
        *(float4*)(wout + e0) = make_float4(
            fmaxf(p0, 0.0f), fmaxf(p1, 0.0f), fmaxf(p2, 0.0f), fmaxf(p3, 0.0f));
    }
}

// ---------------------------------------------------------------------------
// Scan: exclusive prefix sum of cnt[100000] -> rowptr (partial; consumers add
// boff[i>>8] on the fly)
// ---------------------------------------------------------------------------
__device__ __forceinline__ int wave_iscan(int v, int lane)
{
    int incl = v;
    #pragma unroll
    for (int m = 1; m < 64; m <<= 1) {
        int o = __shfl_up(incl, m, 64);
        if (lane >= m) incl += o;
    }
    return incl;
}

__global__ __launch_bounds__(256) void k_scan1(
    const int* __restrict__ cnt, int* __restrict__ rowptr, int* __restrict__ bsum)
{
    __shared__ int wsum[4];
    int t = threadIdx.x, b = blockIdx.x;
    int i = b * 256 + t;
    int lane = t & 63, wid = t >> 6;
    int v = (i < N_NODES) ? cnt[i] : 0;
    int incl = wave_iscan(v, lane);
    if (lane == 63) wsum[wid] = incl;
    __syncthreads();
    int off = 0;
    #pragma unroll
    for (int k = 0; k < 4; ++k) if (k < wid) off += wsum[k];
    if (i < N_NODES) rowptr[i] = off + incl - v;
    if (t == 255) bsum[b] = off + incl;
}

__global__ __launch_bounds__(512) void k_scan2(
    const int* __restrict__ bsum, int* __restrict__ boff, int nblk,
    int* __restrict__ rowptr)
{
    __shared__ int wsum[8];
    int t = threadIdx.x;
    int lane = t & 63, wid = t >> 6;
    int v = (t < nblk) ? bsum[t] : 0;
    int incl = wave_iscan(v, lane);
    if (lane == 63) wsum[wid] = incl;
    __syncthreads();
    int off = 0;
    #pragma unroll
    for (int k = 0; k < 8; ++k) if (k < wid) off += wsum[k];
    if (t < nblk) boff[t] = off + incl - v;
    if (t == 0) rowptr[N_NODES] = N_EDGES;   // final value, no boff add
}

// ---------------------------------------------------------------------------
// CSR placement: pairs[pos] = (src, w); boff folded on the fly
// ---------------------------------------------------------------------------
__global__ __launch_bounds__(256) void k_place(
    const int* __restrict__ ei, const int* __restrict__ rank_pos,
    const int* __restrict__ rowptr, const int* __restrict__ boff,
    const float* __restrict__ wsrc, int2* __restrict__ pairs)
{
    int e = blockIdx.x * 256 + threadIdx.x;
    if (e >= N_EDGES) return;
    int s = ei[e];
    int d = ei[N_EDGES + e];
    int pos = rowptr[d] + boff[d >> 8] + rank_pos[e];
    pairs[pos] = make_int2(s, __float_as_int(wsrc[e]));
}

// ---------------------------------------------------------------------------
// deg via segment-sum (sequential pairs read, NO atomics), 8 lanes per node;
// dis = rsqrt(deg+1); y0 = dis*relu(mask)
// ---------------------------------------------------------------------------
__global__ __launch_bounds__(256) void k_dis_y(
    const int* __restrict__ rowptr, const int* __restrict__ boff,
    const int2* __restrict__ pairs, const float* __restrict__ mask,
    float* __restrict__ dis, float* __restrict__ y)
{
    int t = blockIdx.x * 256 + threadIdx.x;
    int node = t >> 3, l = t & 7;
    if (node >= N_NODES) return;
    int beg = rowptr[node] + boff[node >> 8];
    int np1 = node + 1;
    int end = rowptr[np1] + (np1 < N_NODES ? boff[np1 >> 8] : 0);
    float s = 0.0f;
    for (int j = beg + l; j < end; j += 8)
        s += __int_as_float(pairs[j].y);
    s += __shfl_xor(s, 1, 64);
    s += __shfl_xor(s, 2, 64);
    s += __shfl_xor(s, 4, 64);
    if (l == 0) {
        float di = rsqrtf(fmaxf(s + 1.0f, EPS));   // +1 self-loop
        dis[node] = di;
        y[node] = di * fmaxf(mask[node], 0.0f);
    }
}

// ---------------------------------------------------------------------------
// APPNP step in y-domain, 8 lanes per node, no atomics.
// KEY: ~50% of edge weights are exactly 0 (relu of near-symmetric cosine).
// Predicating the y gather on w!=0 drops those lanes from the exec mask ->
// no L2 line-request issued for them. Exact math (skipped terms are +0.0).
// ---------------------------------------------------------------------------
__global__ __launch_bounds__(256) void k_spmv(
    const int* __restrict__ rowptr, const int* __restrict__ boff,
    const int2* __restrict__ pairs,
    const float* __restrict__ y_in, const float* __restrict__ dis,
    const float* __restrict__ mask, const float* __restrict__ alpha_p,
    float* __restrict__ y_out, float* __restrict__ f_out)
{
    int t = blockIdx.x * 256 + threadIdx.x;
    int node = t >> 3, l = t & 7;
    if (node >= N_NODES) return;
    int beg = rowptr[node] + boff[node >> 8];
    int np1 = node + 1;
    int end = rowptr[np1] + (np1 < N_NODES ? boff[np1 >> 8] : 0);
    float sum = 0.0f;
    for (int j = beg + l; j < end; j += 8) {
        int2 p = pairs[j];
        if (p.y != 0)                       // +0.0f bits == 0; relu emits +0
            sum += __int_as_float(p.y) * y_in[p.x];
    }
    sum += __shfl_xor(sum, 1, 64);
    sum += __shfl_xor(sum, 2, 64);
    sum += __shfl_xor(sum, 4, 64);
    if (l == 0) {
        float di = dis[node];
        float alpha = alpha_p[0];
        float f0 = fmaxf(mask[node], 0.0f);
        float fn = (1.0f - alpha) * di * (sum + y_in[node]) + alpha * f0;
        f_out[node] = fn;
        y_out[node] = di * fn;
    }
}

extern "C" void kernel_launch(void* const* d_in, const int* in_sizes, int n_in,
                              void* d_out, int out_size, void* d_ws, size_t ws_size,
                              hipStream_t stream)
{
    const float* x     = (const float*)d_in[0];
    const float* mask  = (const float*)d_in[1];
    const int*   ei    = (const int*)  d_in[2];
    const float* W     = (const float*)d_in[3];
    const float* b     = (const float*)d_in[4];
    const float* alpha = (const float*)d_in[5];

    float* out_f = (float*)d_out;
    float* out_w = (float*)d_out + N_NODES;

    // workspace layout (float-element offsets)
    float* ws = (float*)d_ws;
    __half* hn     = (__half*)ws;                  // 6.4M halves (3.2M floats)
    int2*  pairs   = (int2*) (ws + 3200000);       // 1.25M x 8B
    int*   rank    = (int*)  (ws + 5700000);       // 1.25M
    int*   cnt     = (int*)  (ws + 6950000);       // 100k
    int*   rowptr  = (int*)  (ws + 7050000);       // 100001 (alloc 100016)
    float* dis     =          ws + 7150016;        // 100k
    float* y_a     =          ws + 7250016;        // 100k
    float* y_b     =          ws + 7350016;        // 100k
    float* f_scr   =          ws + 7450016;        // 100k
    int*   bsum    = (int*)  (ws + 7550016);       // 391 (alloc 512)
    int*   boff    = (int*)  (ws + 7550528);       // 391

    const int edgeBlocks = (N_EDGES + 255) / 256;                         // 4883
    const int segBlocks  = (int)(((long long)N_NODES * 8 + 255) / 256);   // 3125

    // K0: zero(cnt) + gemm_norm fused
    k_gemm_zero<<<ZERO_BLOCKS + GEMM_BLOCKS, 256, 0, stream>>>(x, W, b, hn, cnt);
    // K1: atomic rank  CONCURRENT WITH  edge-order cosine (writes out_w)
    k_rank_cos<<<3 * RANK_BLOCKS, 256, 0, stream>>>(ei, cnt, rank, hn, out_w);
    // K2..K3: rowptr scan (partial rowptr + boff; consumers fold boff on the fly)
    k_scan1<<<NODE_BLOCKS, 256, 0, stream>>>(cnt, rowptr, bsum);
    k_scan2<<<1, 512, 0, stream>>>(bsum, boff, NODE_BLOCKS, rowptr);
    // K4: CSR placement (src, w)
    k_place<<<edgeBlocks, 256, 0, stream>>>(ei, rank, rowptr, boff, out_w, pairs);
    // K5: deg -> dis, y0 (segment-sum, no atomics)
    k_dis_y<<<segBlocks, 256, 0, stream>>>(rowptr, boff, pairs, mask, dis, y_a);

    // K6..K10: 5 APPNP steps in y-domain; last writes f to d_out
    k_spmv<<<segBlocks, 256, 0, stream>>>(rowptr, boff, pairs, y_a, dis, mask, alpha, y_b, f_scr);
    k_spmv<<<segBlocks, 256, 0, stream>>>(rowptr, boff, pairs, y_b, dis, mask, alpha, y_a, f_scr);
    k_spmv<<<segBlocks, 256, 0, stream>>>(rowptr, boff, pairs, y_a, dis, mask, alpha, y_b, f_scr);
    k_spmv<<<segBlocks, 256, 0, stream>>>(rowptr, boff, pairs, y_b, dis, mask, alpha, y_a, f_scr);
    k_spmv<<<segBlocks, 256, 0, stream>>>(rowptr, boff, pairs, y_a, dis, mask, alpha, y_b, out_f);
}

// Round 10
// 209.734 us; speedup vs baseline: 1.4385x; 1.1412x over previous
//
#include <hip/hip_runtime.h>
#include <hip/hip_fp16.h>
#include <math.h>

#define N_NODES 100000
#define N_EDGES 1250000
#define D 64
#define EPS 1e-8f

#define ZERO_BLOCKS 391     // ceil(100000/256)
#define GEMM_BLOCKS 1024
#define NODE_BLOCKS 391     // ceil(100000/256)
#define COSR_BLOCKS 9766    // ceil((N_EDGES/4)*8 / 256)

// ---------------------------------------------------------------------------
// Fused: cnt zeroing (blocks 0..390) + hn = normalize(tanh(xW^T+b)) -> fp16
// ---------------------------------------------------------------------------
__global__ __launch_bounds__(256) void k_gemm_zero(
    const float* __restrict__ x, const float* __restrict__ W,
    const float* __restrict__ b, __half* __restrict__ hn, int* __restrict__ cnt)
{
    if (blockIdx.x < ZERO_BLOCKS) {
        int i = blockIdx.x * 256 + threadIdx.x;
        if (i < N_NODES) cnt[i] = 0;
        return;
    }
    __shared__ float xrow[4][72];
    const int lane = threadIdx.x & 63;
    const int wid  = threadIdx.x >> 6;

    float Wreg[64];
    const float4* Wv = (const float4*)(W + lane * D);
    #pragma unroll
    for (int q = 0; q < 16; ++q) {
        float4 w4 = Wv[q];
        Wreg[4*q+0] = w4.x; Wreg[4*q+1] = w4.y;
        Wreg[4*q+2] = w4.z; Wreg[4*q+3] = w4.w;
    }
    const float bj = b[lane];
    float* xl = xrow[wid];

    const int wave   = (blockIdx.x - ZERO_BLOCKS) * 4 + wid;
    const int nwaves = GEMM_BLOCKS * 4;

    for (int row = wave; row < N_NODES; row += nwaves) {
        float xv = x[(size_t)row * D + lane];
        xl[lane] = xv;
        float acc = bj;
        #pragma unroll
        for (int q = 0; q < 16; ++q) {
            float4 xk4 = *(const float4*)(xl + 4*q);
            acc = fmaf(xk4.x, Wreg[4*q+0], acc);
            acc = fmaf(xk4.y, Wreg[4*q+1], acc);
            acc = fmaf(xk4.z, Wreg[4*q+2], acc);
            acc = fmaf(xk4.w, Wreg[4*q+3], acc);
        }
        float h = tanhf(acc);
        float s = h * h;
        #pragma unroll
        for (int m = 32; m >= 1; m >>= 1) s += __shfl_xor(s, m, 64);
        float nrm = fmaxf(sqrtf(s), EPS);
        hn[(size_t)row * D + lane] = __float2half_rn(h / nrm);
    }
}

// ---------------------------------------------------------------------------
// Fused cosine + NONZERO rank. 8 lanes/edge, 4 edges/group, 8 gathers in
// flight (proven structure). After the butterfly reduce, all 8 lanes of a
// group hold all four w's; lanes sub=0..3 each do the conditional
// atomicAdd(cnt+d) for one edge (only w>0 edges are counted -> compact CSR).
// Atomic return feeds only the rank store (no latency chain into compute).
// ---------------------------------------------------------------------------
__device__ __forceinline__ float dot8h(float4 a, float4 c)
{
    const __half2* ah = (const __half2*)&a;
    const __half2* ch = (const __half2*)&c;
    float p = 0.0f;
    #pragma unroll
    for (int q = 0; q < 4; ++q) {
        float2 af = __half22float2(ah[q]);
        float2 cf = __half22float2(ch[q]);
        p = fmaf(af.x, cf.x, p);
        p = fmaf(af.y, cf.y, p);
    }
    return p;
}

__global__ __launch_bounds__(256) void k_cos_rank(
    const int* __restrict__ ei, const __half* __restrict__ hn,
    int* __restrict__ cnt, int* __restrict__ rank, float* __restrict__ wout)
{
    int t = blockIdx.x * 256 + threadIdx.x;
    int g = t >> 3, sub = t & 7;
    if (g >= N_EDGES / 4) return;
    int e0 = g * 4;
    int4 ss = *(const int4*)(ei + e0);
    int4 dd = *(const int4*)(ei + N_EDGES + e0);

    float4 a0 = ((const float4*)(hn + (size_t)ss.x * D))[sub];
    float4 c0 = ((const float4*)(hn + (size_t)dd.x * D))[sub];
    float4 a1 = ((const float4*)(hn + (size_t)ss.y * D))[sub];
    float4 c1 = ((const float4*)(hn + (size_t)dd.y * D))[sub];
    float4 a2 = ((const float4*)(hn + (size_t)ss.z * D))[sub];
    float4 c2 = ((const float4*)(hn + (size_t)dd.z * D))[sub];
    float4 a3 = ((const float4*)(hn + (size_t)ss.w * D))[sub];
    float4 c3 = ((const float4*)(hn + (size_t)dd.w * D))[sub];

    float p0 = dot8h(a0, c0);
    float p1 = dot8h(a1, c1);
    float p2 = dot8h(a2, c2);
    float p3 = dot8h(a3, c3);
    // butterfly over the 8-lane group: ALL lanes end with the full sums
    p0 += __shfl_xor(p0, 1, 64);  p1 += __shfl_xor(p1, 1, 64);
    p2 += __shfl_xor(p2, 1, 64);  p3 += __shfl_xor(p3, 1, 64);
    p0 += __shfl_xor(p0, 2, 64);  p1 += __shfl_xor(p1, 2, 64);
    p2 += __shfl_xor(p2, 2, 64);  p3 += __shfl_xor(p3, 2, 64);
    p0 += __shfl_xor(p0, 4, 64);  p1 += __shfl_xor(p1, 4, 64);
    p2 += __shfl_xor(p2, 4, 64);  p3 += __shfl_xor(p3, 4, 64);

    float w0 = fmaxf(p0, 0.0f);
    float w1 = fmaxf(p1, 0.0f);
    float w2 = fmaxf(p2, 0.0f);
    float w3 = fmaxf(p3, 0.0f);

    if (sub == 0) {
        *(float4*)(wout + e0) = make_float4(w0, w1, w2, w3);
    }
    if (sub < 4) {
        float w = (sub == 0) ? w0 : (sub == 1) ? w1 : (sub == 2) ? w2 : w3;
        int   d = (sub == 0) ? dd.x : (sub == 1) ? dd.y : (sub == 2) ? dd.z : dd.w;
        int   r = (w > 0.0f) ? atomicAdd(cnt + d, 1) : -1;
        rank[e0 + sub] = r;
    }
}

// ---------------------------------------------------------------------------
// Scan: exclusive prefix sum of cnt[100000] (NONZERO counts) -> rowptr
// (partial; consumers add boff[i>>8] on the fly)
// ---------------------------------------------------------------------------
__device__ __forceinline__ int wave_iscan(int v, int lane)
{
    int incl = v;
    #pragma unroll
    for (int m = 1; m < 64; m <<= 1) {
        int o = __shfl_up(incl, m, 64);
        if (lane >= m) incl += o;
    }
    return incl;
}

__global__ __launch_bounds__(256) void k_scan1(
    const int* __restrict__ cnt, int* __restrict__ rowptr, int* __restrict__ bsum)
{
    __shared__ int wsum[4];
    int t = threadIdx.x, b = blockIdx.x;
    int i = b * 256 + t;
    int lane = t & 63, wid = t >> 6;
    int v = (i < N_NODES) ? cnt[i] : 0;
    int incl = wave_iscan(v, lane);
    if (lane == 63) wsum[wid] = incl;
    __syncthreads();
    int off = 0;
    #pragma unroll
    for (int k = 0; k < 4; ++k) if (k < wid) off += wsum[k];
    if (i < N_NODES) rowptr[i] = off + incl - v;
    if (t == 255) bsum[b] = off + incl;
}

__global__ __launch_bounds__(512) void k_scan2(
    const int* __restrict__ bsum, int* __restrict__ boff, int nblk,
    int* __restrict__ rowptr)
{
    __shared__ int wsum[8];
    int t = threadIdx.x;
    int lane = t & 63, wid = t >> 6;
    int v = (t < nblk) ? bsum[t] : 0;
    int incl = wave_iscan(v, lane);
    if (lane == 63) wsum[wid] = incl;
    __syncthreads();
    int off = 0;
    #pragma unroll
    for (int k = 0; k < 8; ++k) if (k < wid) off += wsum[k];
    if (t < nblk) boff[t] = off + incl - v;
    if (t == nblk - 1) rowptr[N_NODES] = off + incl;   // total NONZERO edges
}

// ---------------------------------------------------------------------------
// CSR placement, COMPACT: only w>0 edges get a slot. Half the scatters.
// ---------------------------------------------------------------------------
__global__ __launch_bounds__(256) void k_place(
    const int* __restrict__ ei, const int* __restrict__ rank_pos,
    const int* __restrict__ rowptr, const int* __restrict__ boff,
    const float* __restrict__ wsrc, int2* __restrict__ pairs)
{
    int e = blockIdx.x * 256 + threadIdx.x;
    if (e >= N_EDGES) return;
    float w = wsrc[e];
    if (!(w > 0.0f)) return;
    int s = ei[e];
    int d = ei[N_EDGES + e];
    int pos = rowptr[d] + boff[d >> 8] + rank_pos[e];
    pairs[pos] = make_int2(s, __float_as_int(w));
}

// ---------------------------------------------------------------------------
// deg via segment-sum over COMPACT rows (zeros contribute nothing anyway),
// 8 lanes per node; dis = rsqrt(deg+1); y0 = dis*relu(mask)
// ---------------------------------------------------------------------------
__global__ __launch_bounds__(256) void k_dis_y(
    const int* __restrict__ rowptr, const int* __restrict__ boff,
    const int2* __restrict__ pairs, const float* __restrict__ mask,
    float* __restrict__ dis, float* __restrict__ y)
{
    int t = blockIdx.x * 256 + threadIdx.x;
    int node = t >> 3, l = t & 7;
    if (node >= N_NODES) return;
    int beg = rowptr[node] + boff[node >> 8];
    int np1 = node + 1;
    int end = rowptr[np1] + (np1 < N_NODES ? boff[np1 >> 8] : 0);
    float s = 0.0f;
    for (int j = beg + l; j < end; j += 8)
        s += __int_as_float(pairs[j].y);
    s += __shfl_xor(s, 1, 64);
    s += __shfl_xor(s, 2, 64);
    s += __shfl_xor(s, 4, 64);
    if (l == 0) {
        float di = rsqrtf(fmaxf(s + 1.0f, EPS));   // +1 self-loop
        dis[node] = di;
        y[node] = di * fmaxf(mask[node], 0.0f);
    }
}

// ---------------------------------------------------------------------------
// APPNP step in y-domain over COMPACT rows (avg nonzero degree ~6.25,
// 8 lanes/node -> mostly single iteration), no atomics:
// f'_i = (1-a) * dis_i * ( sum_j w_ij*y_j + y_i ) + a*relu(mask_i)
// y'_i = dis_i * f'_i
// ---------------------------------------------------------------------------
__global__ __launch_bounds__(256) void k_spmv(
    const int* __restrict__ rowptr, const int* __restrict__ boff,
    const int2* __restrict__ pairs,
    const float* __restrict__ y_in, const float* __restrict__ dis,
    const float* __restrict__ mask, const float* __restrict__ alpha_p,
    float* __restrict__ y_out, float* __restrict__ f_out)
{
    int t = blockIdx.x * 256 + threadIdx.x;
    int node = t >> 3, l = t & 7;
    if (node >= N_NODES) return;
    int beg = rowptr[node] + boff[node >> 8];
    int np1 = node + 1;
    int end = rowptr[np1] + (np1 < N_NODES ? boff[np1 >> 8] : 0);
    float sum = 0.0f;
    for (int j = beg + l; j < end; j += 8) {
        int2 p = pairs[j];
        sum += __int_as_float(p.y) * y_in[p.x];
    }
    sum += __shfl_xor(sum, 1, 64);
    sum += __shfl_xor(sum, 2, 64);
    sum += __shfl_xor(sum, 4, 64);
    if (l == 0) {
        float di = dis[node];
        float alpha = alpha_p[0];
        float f0 = fmaxf(mask[node], 0.0f);
        float fn = (1.0f - alpha) * di * (sum + y_in[node]) + alpha * f0;
        f_out[node] = fn;
        y_out[node] = di * fn;
    }
}

extern "C" void kernel_launch(void* const* d_in, const int* in_sizes, int n_in,
                              void* d_out, int out_size, void* d_ws, size_t ws_size,
                              hipStream_t stream)
{
    const float* x     = (const float*)d_in[0];
    const float* mask  = (const float*)d_in[1];
    const int*   ei    = (const int*)  d_in[2];
    const float* W     = (const float*)d_in[3];
    const float* b     = (const float*)d_in[4];
    const float* alpha = (const float*)d_in[5];

    float* out_f = (float*)d_out;
    float* out_w = (float*)d_out + N_NODES;

    // workspace layout (float-element offsets)
    float* ws = (float*)d_ws;
    __half* hn     = (__half*)ws;                  // 6.4M halves (3.2M floats)
    int2*  pairs   = (int2*) (ws + 3200000);       // <=1.25M x 8B (compact)
    int*   rank    = (int*)  (ws + 5700000);       // 1.25M
    int*   cnt     = (int*)  (ws + 6950000);       // 100k
    int*   rowptr  = (int*)  (ws + 7050000);       // 100001 (alloc 100016)
    float* dis     =          ws + 7150016;        // 100k
    float* y_a     =          ws + 7250016;        // 100k
    float* y_b     =          ws + 7350016;        // 100k
    float* f_scr   =          ws + 7450016;        // 100k
    int*   bsum    = (int*)  (ws + 7550016);       // 391 (alloc 512)
    int*   boff    = (int*)  (ws + 7550528);       // 391

    const int edgeBlocks = (N_EDGES + 255) / 256;                         // 4883
    const int segBlocks  = (int)(((long long)N_NODES * 8 + 255) / 256);   // 3125

    // K0: zero(cnt) + gemm_norm fused
    k_gemm_zero<<<ZERO_BLOCKS + GEMM_BLOCKS, 256, 0, stream>>>(x, W, b, hn, cnt);
    // K1: cosine + nonzero-rank fused (writes out_w, rank, cnt)
    k_cos_rank<<<COSR_BLOCKS, 256, 0, stream>>>(ei, hn, cnt, rank, out_w);
    // K2..K3: rowptr scan (partial rowptr + boff; consumers fold boff on the fly)
    k_scan1<<<NODE_BLOCKS, 256, 0, stream>>>(cnt, rowptr, bsum);
    k_scan2<<<1, 512, 0, stream>>>(bsum, boff, NODE_BLOCKS, rowptr);
    // K4: compact CSR placement (src, w), w>0 only
    k_place<<<edgeBlocks, 256, 0, stream>>>(ei, rank, rowptr, boff, out_w, pairs);
    // K5: deg -> dis, y0 (segment-sum, no atomics)
    k_dis_y<<<segBlocks, 256, 0, stream>>>(rowptr, boff, pairs, mask, dis, y_a);

    // K6..K10: 5 APPNP steps in y-domain; last writes f to d_out
    k_spmv<<<segBlocks, 256, 0, stream>>>(rowptr, boff, pairs, y_a, dis, mask, alpha, y_b, f_scr);
    k_spmv<<<segBlocks, 256, 0, stream>>>(rowptr, boff, pairs, y_b, dis, mask, alpha, y_a, f_scr);
    k_spmv<<<segBlocks, 256, 0, stream>>>(rowptr, boff, pairs, y_a, dis, mask, alpha, y_b, f_scr);
    k_spmv<<<segBlocks, 256, 0, stream>>>(rowptr, boff, pairs, y_b, dis, mask, alpha, y_a, f_scr);
    k_spmv<<<segBlocks, 256, 0, stream>>>(rowptr, boff, pairs, y_a, dis, mask, alpha, y_b, out_f);
}

// Round 11
// 208.139 us; speedup vs baseline: 1.4495x; 1.0077x over previous
//
#include <hip/hip_runtime.h>
#include <hip/hip_fp16.h>
#include <math.h>

#define N_NODES 100000
#define N_EDGES 1250000
#define D 64
#define EPS 1e-8f

#define ZERO_BLOCKS 391     // ceil(100000/256)
#define GEMM_BLOCKS 1024
#define NODE_BLOCKS 391     // ceil(100000/256)
#define COSR_BLOCKS 9766    // ceil((N_EDGES/4)*8 / 256)

// ---------------------------------------------------------------------------
// Fused: cnt zeroing (blocks 0..390) + hn = normalize(tanh(xW^T+b)) -> fp16
// ---------------------------------------------------------------------------
__global__ __launch_bounds__(256) void k_gemm_zero(
    const float* __restrict__ x, const float* __restrict__ W,
    const float* __restrict__ b, __half* __restrict__ hn, int* __restrict__ cnt)
{
    if (blockIdx.x < ZERO_BLOCKS) {
        int i = blockIdx.x * 256 + threadIdx.x;
        if (i < N_NODES) cnt[i] = 0;
        return;
    }
    __shared__ float xrow[4][72];
    const int lane = threadIdx.x & 63;
    const int wid  = threadIdx.x >> 6;

    float Wreg[64];
    const float4* Wv = (const float4*)(W + lane * D);
    #pragma unroll
    for (int q = 0; q < 16; ++q) {
        float4 w4 = Wv[q];
        Wreg[4*q+0] = w4.x; Wreg[4*q+1] = w4.y;
        Wreg[4*q+2] = w4.z; Wreg[4*q+3] = w4.w;
    }
    const float bj = b[lane];
    float* xl = xrow[wid];

    const int wave   = (blockIdx.x - ZERO_BLOCKS) * 4 + wid;
    const int nwaves = GEMM_BLOCKS * 4;

    for (int row = wave; row < N_NODES; row += nwaves) {
        float xv = x[(size_t)row * D + lane];
        xl[lane] = xv;
        float acc = bj;
        #pragma unroll
        for (int q = 0; q < 16; ++q) {
            float4 xk4 = *(const float4*)(xl + 4*q);
            acc = fmaf(xk4.x, Wreg[4*q+0], acc);
            acc = fmaf(xk4.y, Wreg[4*q+1], acc);
            acc = fmaf(xk4.z, Wreg[4*q+2], acc);
            acc = fmaf(xk4.w, Wreg[4*q+3], acc);
        }
        float h = tanhf(acc);
        float s = h * h;
        #pragma unroll
        for (int m = 32; m >= 1; m >>= 1) s += __shfl_xor(s, m, 64);
        float nrm = fmaxf(sqrtf(s), EPS);
        hn[(size_t)row * D + lane] = __float2half_rn(h / nrm);
    }
}

// ---------------------------------------------------------------------------
// Fused cosine + NONZERO rank. 8 lanes/edge, 4 edges/group, 8 gathers in
// flight. Only w>0 edges are counted (compact CSR); rank stored only for
// w>0 edges (zero-edge ranks are never read by k_place).
// ---------------------------------------------------------------------------
__device__ __forceinline__ float dot8h(float4 a, float4 c)
{
    const __half2* ah = (const __half2*)&a;
    const __half2* ch = (const __half2*)&c;
    float p = 0.0f;
    #pragma unroll
    for (int q = 0; q < 4; ++q) {
        float2 af = __half22float2(ah[q]);
        float2 cf = __half22float2(ch[q]);
        p = fmaf(af.x, cf.x, p);
        p = fmaf(af.y, cf.y, p);
    }
    return p;
}

__global__ __launch_bounds__(256) void k_cos_rank(
    const int* __restrict__ ei, const __half* __restrict__ hn,
    int* __restrict__ cnt, int* __restrict__ rank, float* __restrict__ wout)
{
    int t = blockIdx.x * 256 + threadIdx.x;
    int g = t >> 3, sub = t & 7;
    if (g >= N_EDGES / 4) return;
    int e0 = g * 4;
    int4 ss = *(const int4*)(ei + e0);
    int4 dd = *(const int4*)(ei + N_EDGES + e0);

    float4 a0 = ((const float4*)(hn + (size_t)ss.x * D))[sub];
    float4 c0 = ((const float4*)(hn + (size_t)dd.x * D))[sub];
    float4 a1 = ((const float4*)(hn + (size_t)ss.y * D))[sub];
    float4 c1 = ((const float4*)(hn + (size_t)dd.y * D))[sub];
    float4 a2 = ((const float4*)(hn + (size_t)ss.z * D))[sub];
    float4 c2 = ((const float4*)(hn + (size_t)dd.z * D))[sub];
    float4 a3 = ((const float4*)(hn + (size_t)ss.w * D))[sub];
    float4 c3 = ((const float4*)(hn + (size_t)dd.w * D))[sub];

    float p0 = dot8h(a0, c0);
    float p1 = dot8h(a1, c1);
    float p2 = dot8h(a2, c2);
    float p3 = dot8h(a3, c3);
    // butterfly over the 8-lane group: ALL lanes end with the full sums
    p0 += __shfl_xor(p0, 1, 64);  p1 += __shfl_xor(p1, 1, 64);
    p2 += __shfl_xor(p2, 1, 64);  p3 += __shfl_xor(p3, 1, 64);
    p0 += __shfl_xor(p0, 2, 64);  p1 += __shfl_xor(p1, 2, 64);
    p2 += __shfl_xor(p2, 2, 64);  p3 += __shfl_xor(p3, 2, 64);
    p0 += __shfl_xor(p0, 4, 64);  p1 += __shfl_xor(p1, 4, 64);
    p2 += __shfl_xor(p2, 4, 64);  p3 += __shfl_xor(p3, 4, 64);

    float w0 = fmaxf(p0, 0.0f);
    float w1 = fmaxf(p1, 0.0f);
    float w2 = fmaxf(p2, 0.0f);
    float w3 = fmaxf(p3, 0.0f);

    if (sub == 0) {
        *(float4*)(wout + e0) = make_float4(w0, w1, w2, w3);
    }
    if (sub < 4) {
        float w = (sub == 0) ? w0 : (sub == 1) ? w1 : (sub == 2) ? w2 : w3;
        int   d = (sub == 0) ? dd.x : (sub == 1) ? dd.y : (sub == 2) ? dd.z : dd.w;
        if (w > 0.0f)
            rank[e0 + sub] = atomicAdd(cnt + d, 1);
    }
}

// ---------------------------------------------------------------------------
// Scan: exclusive prefix sum of cnt[100000] (NONZERO counts) -> rowptr
// (partial; consumers add boff[i>>8] on the fly)
// ---------------------------------------------------------------------------
__device__ __forceinline__ int wave_iscan(int v, int lane)
{
    int incl = v;
    #pragma unroll
    for (int m = 1; m < 64; m <<= 1) {
        int o = __shfl_up(incl, m, 64);
        if (lane >= m) incl += o;
    }
    return incl;
}

__global__ __launch_bounds__(256) void k_scan1(
    const int* __restrict__ cnt, int* __restrict__ rowptr, int* __restrict__ bsum)
{
    __shared__ int wsum[4];
    int t = threadIdx.x, b = blockIdx.x;
    int i = b * 256 + t;
    int lane = t & 63, wid = t >> 6;
    int v = (i < N_NODES) ? cnt[i] : 0;
    int incl = wave_iscan(v, lane);
    if (lane == 63) wsum[wid] = incl;
    __syncthreads();
    int off = 0;
    #pragma unroll
    for (int k = 0; k < 4; ++k) if (k < wid) off += wsum[k];
    if (i < N_NODES) rowptr[i] = off + incl - v;
    if (t == 255) bsum[b] = off + incl;
}

__global__ __launch_bounds__(512) void k_scan2(
    const int* __restrict__ bsum, int* __restrict__ boff, int nblk,
    int* __restrict__ rowptr)
{
    __shared__ int wsum[8];
    int t = threadIdx.x;
    int lane = t & 63, wid = t >> 6;
    int v = (t < nblk) ? bsum[t] : 0;
    int incl = wave_iscan(v, lane);
    if (lane == 63) wsum[wid] = incl;
    __syncthreads();
    int off = 0;
    #pragma unroll
    for (int k = 0; k < 8; ++k) if (k < wid) off += wsum[k];
    if (t < nblk) boff[t] = off + incl - v;
    if (t == nblk - 1) rowptr[N_NODES] = off + incl;   // total NONZERO edges
}

// ---------------------------------------------------------------------------
// CSR placement, COMPACT: only w>0 edges get a slot.
// ---------------------------------------------------------------------------
__global__ __launch_bounds__(256) void k_place(
    const int* __restrict__ ei, const int* __restrict__ rank_pos,
    const int* __restrict__ rowptr, const int* __restrict__ boff,
    const float* __restrict__ wsrc, int2* __restrict__ pairs)
{
    int e = blockIdx.x * 256 + threadIdx.x;
    if (e >= N_EDGES) return;
    float w = wsrc[e];
    if (!(w > 0.0f)) return;
    int s = ei[e];
    int d = ei[N_EDGES + e];
    int pos = rowptr[d] + boff[d >> 8] + rank_pos[e];
    pairs[pos] = make_int2(s, __float_as_int(w));
}

// ---------------------------------------------------------------------------
// deg via segment-sum over COMPACT rows, 4 lanes/node x 2 slots unrolled
// (covers deg<=8 in one shot); dis = rsqrt(deg+1); y0 = dis*relu(mask)
// ---------------------------------------------------------------------------
__global__ __launch_bounds__(256) void k_dis_y(
    const int* __restrict__ rowptr, const int* __restrict__ boff,
    const int2* __restrict__ pairs, const float* __restrict__ mask,
    float* __restrict__ dis, float* __restrict__ y)
{
    int t = blockIdx.x * 256 + threadIdx.x;
    int node = t >> 2, l = t & 3;
    if (node >= N_NODES) return;
    int beg = rowptr[node] + boff[node >> 8];
    int np1 = node + 1;
    int end = rowptr[np1] + (np1 < N_NODES ? boff[np1 >> 8] : 0);
    float s = 0.0f;
    for (int j = beg + l; j < end; j += 8) {
        int2 p0 = pairs[j];
        int j2 = j + 4;
        int2 p1 = make_int2(0, 0);
        if (j2 < end) p1 = pairs[j2];
        s += __int_as_float(p0.y);
        s += __int_as_float(p1.y);
    }
    s += __shfl_xor(s, 1, 64);
    s += __shfl_xor(s, 2, 64);
    if (l == 0) {
        float di = rsqrtf(fmaxf(s + 1.0f, EPS));   // +1 self-loop
        dis[node] = di;
        y[node] = di * fmaxf(mask[node], 0.0f);
    }
}

// ---------------------------------------------------------------------------
// APPNP step, 4 lanes/node x 2 slots unrolled: two pairs-loads issue
// independently, then two y-gathers in flight per lane (2x MLP vs 8-lane).
// f written only when f_out != nullptr (final step).
// ---------------------------------------------------------------------------
__global__ __launch_bounds__(256) void k_spmv(
    const int* __restrict__ rowptr, const int* __restrict__ boff,
    const int2* __restrict__ pairs,
    const float* __restrict__ y_in, const float* __restrict__ dis,
    const float* __restrict__ mask, const float* __restrict__ alpha_p,
    float* __restrict__ y_out, float* __restrict__ f_out)
{
    int t = blockIdx.x * 256 + threadIdx.x;
    int node = t >> 2, l = t & 3;
    if (node >= N_NODES) return;
    int beg = rowptr[node] + boff[node >> 8];
    int np1 = node + 1;
    int end = rowptr[np1] + (np1 < N_NODES ? boff[np1 >> 8] : 0);
    float sum = 0.0f;
    for (int j = beg + l; j < end; j += 8) {
        int2 p0 = pairs[j];
        int j2 = j + 4;
        int2 p1 = make_int2(0, 0);
        if (j2 < end) p1 = pairs[j2];
        sum += __int_as_float(p0.y) * y_in[p0.x];
        sum += __int_as_float(p1.y) * y_in[p1.x];   // p1=(0,0) adds 0*y[0]
    }
    sum += __shfl_xor(sum, 1, 64);
    sum += __shfl_xor(sum, 2, 64);
    if (l == 0) {
        float di = dis[node];
        float alpha = alpha_p[0];
        float f0 = fmaxf(mask[node], 0.0f);
        float fn = (1.0f - alpha) * di * (sum + y_in[node]) + alpha * f0;
        if (f_out) f_out[node] = fn;
        y_out[node] = di * fn;
    }
}

extern "C" void kernel_launch(void* const* d_in, const int* in_sizes, int n_in,
                              void* d_out, int out_size, void* d_ws, size_t ws_size,
                              hipStream_t stream)
{
    const float* x     = (const float*)d_in[0];
    const float* mask  = (const float*)d_in[1];
    const int*   ei    = (const int*)  d_in[2];
    const float* W     = (const float*)d_in[3];
    const float* b     = (const float*)d_in[4];
    const float* alpha = (const float*)d_in[5];

    float* out_f = (float*)d_out;
    float* out_w = (float*)d_out + N_NODES;

    // workspace layout (float-element offsets)
    float* ws = (float*)d_ws;
    __half* hn     = (__half*)ws;                  // 6.4M halves (3.2M floats)
    int2*  pairs   = (int2*) (ws + 3200000);       // <=1.25M x 8B (compact)
    int*   rank    = (int*)  (ws + 5700000);       // 1.25M
    int*   cnt     = (int*)  (ws + 6950000);       // 100k
    int*   rowptr  = (int*)  (ws + 7050000);       // 100001 (alloc 100016)
    float* dis     =          ws + 7150016;        // 100k
    float* y_a     =          ws + 7250016;        // 100k
    float* y_b     =          ws + 7350016;        // 100k
    int*   bsum    = (int*)  (ws + 7550016);       // 391 (alloc 512)
    int*   boff    = (int*)  (ws + 7550528);       // 391

    const int edgeBlocks = (N_EDGES + 255) / 256;                         // 4883
    const int segBlocks  = (int)(((long long)N_NODES * 4 + 255) / 256);   // 1563

    // K0: zero(cnt) + gemm_norm fused
    k_gemm_zero<<<ZERO_BLOCKS + GEMM_BLOCKS, 256, 0, stream>>>(x, W, b, hn, cnt);
    // K1: cosine + nonzero-rank fused (writes out_w, rank, cnt)
    k_cos_rank<<<COSR_BLOCKS, 256, 0, stream>>>(ei, hn, cnt, rank, out_w);
    // K2..K3: rowptr scan (partial rowptr + boff; consumers fold boff on the fly)
    k_scan1<<<NODE_BLOCKS, 256, 0, stream>>>(cnt, rowptr, bsum);
    k_scan2<<<1, 512, 0, stream>>>(bsum, boff, NODE_BLOCKS, rowptr);
    // K4: compact CSR placement (src, w), w>0 only
    k_place<<<edgeBlocks, 256, 0, stream>>>(ei, rank, rowptr, boff, out_w, pairs);
    // K5: deg -> dis, y0 (segment-sum, no atomics)
    k_dis_y<<<segBlocks, 256, 0, stream>>>(rowptr, boff, pairs, mask, dis, y_a);

    // K6..K10: 5 APPNP steps in y-domain; last writes f to d_out
    k_spmv<<<segBlocks, 256, 0, stream>>>(rowptr, boff, pairs, y_a, dis, mask, alpha, y_b, (float*)nullptr);
    k_spmv<<<segBlocks, 256, 0, stream>>>(rowptr, boff, pairs, y_b, dis, mask, alpha, y_a, (float*)nullptr);
    k_spmv<<<segBlocks, 256, 0, stream>>>(rowptr, boff, pairs, y_a, dis, mask, alpha, y_b, (float*)nullptr);
    k_spmv<<<segBlocks, 256, 0, stream>>>(rowptr, boff, pairs, y_b, dis, mask, alpha, y_a, (float*)nullptr);
    k_spmv<<<segBlocks, 256, 0, stream>>>(rowptr, boff, pairs, y_a, dis, mask, alpha, y_b, out_f);
}